// Round 1
// baseline (397.707 us; speedup 1.0000x reference)
//
#include <hip/hip_runtime.h>
#include <hip/hip_bf16.h>

typedef short bf16x8 __attribute__((ext_vector_type(8)));
typedef float f32x4 __attribute__((ext_vector_type(4)));

__device__ inline unsigned short f2bf(float f) {
    union { float f; unsigned u; } c; c.f = f;
    unsigned r = c.u + 0x7fffu + ((c.u >> 16) & 1u);
    return (unsigned short)(r >> 16);
}

// ---------- fp32 -> bf16 convert (x4 vectorized) ----------
__global__ __launch_bounds__(256) void k_f32_to_bf16(const float* __restrict__ in,
                                                     unsigned short* __restrict__ out, int n4) {
    int i = blockIdx.x * 256 + threadIdx.x;
    if (i >= n4) return;
    f32x4 v = *(const f32x4*)&in[(size_t)i * 4];
    ushort4 o;
    o.x = f2bf(v[0]); o.y = f2bf(v[1]); o.z = f2bf(v[2]); o.w = f2bf(v[3]);
    *(ushort4*)&out[(size_t)i * 4] = o;
}

// ---------- transpose [K][N] fp32 -> [N][K] bf16 (small weights, naive) ----------
__global__ __launch_bounds__(256) void k_transpose_bf16(const float* __restrict__ in,
                                                        unsigned short* __restrict__ out,
                                                        int K, int N) {
    int idx = blockIdx.x * 256 + threadIdx.x;  // out index, k fastest
    if (idx >= N * K) return;
    int n = idx / K, k = idx % K;
    out[idx] = f2bf(in[(size_t)k * N + n]);
}

// ---------- transpose V slice of qkv -> v_t[b,h,d,j] bf16 ----------
__global__ __launch_bounds__(256) void transpose_v(const unsigned short* __restrict__ qkv,
                                                   unsigned short* __restrict__ vt) {
    const int bh = blockIdx.y, b = bh >> 3, h = bh & 7;
    const int j0 = blockIdx.x * 64;
    __shared__ unsigned short tile[64][72];
    const int t = threadIdx.x;
#pragma unroll
    for (int it = 0; it < 16; ++it) {
        int idx = it * 256 + t;
        int jr = idx >> 6, col = idx & 63;
        tile[jr][col] = qkv[(size_t)(b * 1024 + j0 + jr) * 1536 + 1024 + h * 64 + col];
    }
    __syncthreads();
#pragma unroll
    for (int it = 0; it < 16; ++it) {
        int idx = it * 256 + t;
        int dr = idx >> 6, jc = idx & 63;
        vt[((size_t)bh * 64 + dr) * 1024 + j0 + jc] = tile[jc][dr];
    }
}

// ---------- generic A[M,K] * B^T[N,K] bf16 MFMA GEMM, batched, exact tiling ----------
template <int BM, int BN, int BK, bool OUT_BF16, bool HAS_BIAS>
__global__ __launch_bounds__(256) void gemm_bt(
    const unsigned short* __restrict__ A, int ldA, long long sA,
    const unsigned short* __restrict__ B, int ldB, long long sB,
    void* __restrict__ Cv, int ldC, long long sC,
    const float* __restrict__ bias, float scale, int K) {
    constexpr int PAD = 8, LDR = BK + PAD;
    __shared__ __align__(16) unsigned short As[BM * LDR];
    __shared__ __align__(16) unsigned short Bs[BN * LDR];

    const int tid = threadIdx.x;
    const int lane = tid & 63, wv = tid >> 6;
    const int wm = wv >> 1, wn = wv & 1;
    constexpr int WM = BM / 2, WN = BN / 2;
    constexpr int MF = WM / 16, NF = WN / 16;
    constexpr int KG = BK / 8;

    const int m0 = blockIdx.x * BM, n0 = blockIdx.y * BN;
    A += (long long)blockIdx.z * sA;
    B += (long long)blockIdx.z * sB;

    const int lr = lane & 15, lk = (lane >> 4) * 8;

    f32x4 acc[MF][NF];
#pragma unroll
    for (int m = 0; m < MF; ++m)
#pragma unroll
        for (int n = 0; n < NF; ++n) acc[m][n] = (f32x4){0.f, 0.f, 0.f, 0.f};

    for (int k0 = 0; k0 < K; k0 += BK) {
#pragma unroll
        for (int i = 0; i < BM * KG / 256; ++i) {
            int c = i * 256 + tid;
            int row = c / KG, kg = c % KG;
            *(bf16x8*)&As[row * LDR + kg * 8] =
                *(const bf16x8*)&A[(size_t)(m0 + row) * ldA + k0 + kg * 8];
        }
#pragma unroll
        for (int i = 0; i < BN * KG / 256; ++i) {
            int c = i * 256 + tid;
            int row = c / KG, kg = c % KG;
            *(bf16x8*)&Bs[row * LDR + kg * 8] =
                *(const bf16x8*)&B[(size_t)(n0 + row) * ldB + k0 + kg * 8];
        }
        __syncthreads();
#pragma unroll
        for (int kk = 0; kk < BK; kk += 32) {
            bf16x8 af[MF], bfr[NF];
#pragma unroll
            for (int m = 0; m < MF; ++m)
                af[m] = *(const bf16x8*)&As[(wm * WM + m * 16 + lr) * LDR + kk + lk];
#pragma unroll
            for (int n = 0; n < NF; ++n)
                bfr[n] = *(const bf16x8*)&Bs[(wn * WN + n * 16 + lr) * LDR + kk + lk];
#pragma unroll
            for (int m = 0; m < MF; ++m)
#pragma unroll
                for (int n = 0; n < NF; ++n)
                    acc[m][n] = __builtin_amdgcn_mfma_f32_16x16x32_bf16(af[m], bfr[n], acc[m][n], 0, 0, 0);
        }
        __syncthreads();
    }

    const int rb = (lane >> 4) * 4;
    const long long cbase = (long long)blockIdx.z * sC;
#pragma unroll
    for (int m = 0; m < MF; ++m) {
#pragma unroll
        for (int n = 0; n < NF; ++n) {
            int col = n0 + wn * WN + n * 16 + lr;
            float bv = HAS_BIAS ? bias[col] : 0.0f;
#pragma unroll
            for (int r = 0; r < 4; ++r) {
                int row = m0 + wm * WM + m * 16 + rb + r;
                float v = acc[m][n][r] * scale + bv;
                if constexpr (OUT_BF16)
                    ((unsigned short*)Cv)[cbase + (size_t)row * ldC + col] = f2bf(v);
                else
                    ((float*)Cv)[cbase + (size_t)row * ldC + col] = v;
            }
        }
    }
}

// ---------- fused softmax + cross-head remix + head-LayerNorm (per (b,i) row) ----------
__global__ __launch_bounds__(256) void softmax_remix_ln(
    const float* __restrict__ dots,      // [8][1024][1024] for this b
    unsigned short* __restrict__ re,     // bf16 [8][1024][1024]
    const float* __restrict__ Wm,        // [8][8]
    const float* __restrict__ g_, const float* __restrict__ bb_) {
    constexpr int N = 1024;
    const int i = blockIdx.x, t = threadIdx.x;
    const int lane = t & 63, wv = t >> 6;
    __shared__ float sW[64], sg[8], sb[8];
    __shared__ float redm[4][8], reds[4][8];
    if (t < 64) sW[t] = Wm[t];
    if (t < 8) { sg[t] = g_[t]; sb[t] = bb_[t]; }

    f32x4 v[8];
    const float* base = dots + (size_t)i * N + t * 4;
#pragma unroll
    for (int h = 0; h < 8; ++h) v[h] = *(const f32x4*)(base + (size_t)h * N * N);

    float mh[8];
#pragma unroll
    for (int h = 0; h < 8; ++h) {
        float x = fmaxf(fmaxf(v[h][0], v[h][1]), fmaxf(v[h][2], v[h][3]));
#pragma unroll
        for (int o = 32; o; o >>= 1) x = fmaxf(x, __shfl_xor(x, o));
        mh[h] = x;
    }
    if (lane == 0) {
#pragma unroll
        for (int h = 0; h < 8; ++h) redm[wv][h] = mh[h];
    }
    __syncthreads();

    float sh[8];
#pragma unroll
    for (int h = 0; h < 8; ++h) {
        float m = fmaxf(fmaxf(redm[0][h], redm[1][h]), fmaxf(redm[2][h], redm[3][h]));
        f32x4 e;
        e[0] = __expf(v[h][0] - m);
        e[1] = __expf(v[h][1] - m);
        e[2] = __expf(v[h][2] - m);
        e[3] = __expf(v[h][3] - m);
        v[h] = e;
        float s = e[0] + e[1] + e[2] + e[3];
#pragma unroll
        for (int o = 32; o; o >>= 1) s += __shfl_xor(s, o);
        sh[h] = s;
    }
    if (lane == 0) {
#pragma unroll
        for (int h = 0; h < 8; ++h) reds[wv][h] = sh[h];
    }
    __syncthreads();
#pragma unroll
    for (int h = 0; h < 8; ++h) {
        float s = reds[0][h] + reds[1][h] + reds[2][h] + reds[3][h];
        float inv = 1.0f / s;
        v[h] = v[h] * inv;
    }

    unsigned short outp[8][4];
#pragma unroll
    for (int c = 0; c < 4; ++c) {
        float mix[8], mu = 0.f;
#pragma unroll
        for (int g = 0; g < 8; ++g) {
            float a = 0.f;
#pragma unroll
            for (int h = 0; h < 8; ++h) a += v[h][c] * sW[h * 8 + g];
            mix[g] = a; mu += a;
        }
        mu *= 0.125f;
        float var = 0.f;
#pragma unroll
        for (int g = 0; g < 8; ++g) { float d = mix[g] - mu; var += d * d; }
        var *= 0.125f;
        float rs = rsqrtf(var + 1e-5f);
#pragma unroll
        for (int g = 0; g < 8; ++g)
            outp[g][c] = f2bf((mix[g] - mu) * rs * sg[g] + sb[g]);
    }
#pragma unroll
    for (int g = 0; g < 8; ++g) {
        ushort4 o; o.x = outp[g][0]; o.y = outp[g][1]; o.z = outp[g][2]; o.w = outp[g][3];
        *(ushort4*)&re[(size_t)g * N * N + (size_t)i * N + t * 4] = o;
    }
}

extern "C" void kernel_launch(void* const* d_in, const int* in_sizes, int n_in,
                              void* d_out, int out_size, void* d_ws, size_t ws_size,
                              hipStream_t stream) {
    const float* x        = (const float*)d_in[0];
    const float* w_qkv    = (const float*)d_in[1];
    const float* reattn_w = (const float*)d_in[2];
    const float* ln_g     = (const float*)d_in[3];
    const float* ln_b     = (const float*)d_in[4];
    const float* w_out    = (const float*)d_in[5];
    const float* b_out    = (const float*)d_in[6];
    float* out = (float*)d_out;

    char* ws = (char*)d_ws;
    unsigned short* x_bf  = (unsigned short*)(ws + 0);          //  8 MB  [8192][512]
    unsigned short* wqkvT = (unsigned short*)(ws + 8388608);    //  1.5MB [1536][512]
    unsigned short* woutT = (unsigned short*)(ws + 9961472);    //  0.5MB [512][512]
    unsigned short* qkv   = (unsigned short*)(ws + 10485760);   // 24 MB  [8192][1536]
    unsigned short* v_t   = (unsigned short*)(ws + 35651584);   //  8 MB  [64][64][1024]
    unsigned short* pv    = (unsigned short*)(ws + 44040192);   //  8 MB  [8192][512]
    float*          dots  = (float*)(ws + 52428800);            // 32 MB  [8][1024][1024]
    unsigned short* rea   = (unsigned short*)(ws + 85983232);   // 16 MB  [8][1024][1024]

    // convert / transpose weights
    k_f32_to_bf16<<<4096, 256, 0, stream>>>(x, x_bf, 1048576);
    k_transpose_bf16<<<3072, 256, 0, stream>>>(w_qkv, wqkvT, 512, 1536);
    k_transpose_bf16<<<1024, 256, 0, stream>>>(w_out, woutT, 512, 512);

    // qkv = x @ w_qkv   (M=8192, N=1536, K=512)
    gemm_bt<128, 128, 64, true, false><<<dim3(64, 12, 1), 256, 0, stream>>>(
        x_bf, 512, 0, wqkvT, 512, 0, qkv, 1536, 0, nullptr, 1.0f, 512);

    transpose_v<<<dim3(16, 64), 256, 0, stream>>>(qkv, v_t);

    for (int b = 0; b < 8; ++b) {
        const unsigned short* qb = qkv + (size_t)b * 1024 * 1536;
        // dots[h,i,j] = scale * q_i . k_j   (batch=h, M=N=1024, K=64)
        gemm_bt<128, 128, 64, false, false><<<dim3(8, 8, 8), 256, 0, stream>>>(
            qb, 1536, 64, qb + 512, 1536, 64, dots, 1024, 1048576, nullptr, 0.125f, 64);
        // softmax over j, remix over heads, LN over heads
        softmax_remix_ln<<<1024, 256, 0, stream>>>(dots, rea, reattn_w, ln_g, ln_b);
        // pv[b,i,h*64+d] = sum_j rea[h,i,j] * v[h,j,d]   (batch=h, M=1024, N=64, K=1024)
        gemm_bt<128, 64, 64, true, false><<<dim3(8, 1, 8), 256, 0, stream>>>(
            rea, 1024, 1048576, v_t + (size_t)b * 8 * 65536, 1024, 65536,
            pv + (size_t)b * 1024 * 512, 512, 64, nullptr, 1.0f, 1024);
    }

    // out = pv @ w_out + b_out   (M=8192, N=512, K=512), fp32 out
    gemm_bt<128, 128, 64, false, true><<<dim3(64, 4, 1), 256, 0, stream>>>(
        pv, 512, 0, woutT, 512, 0, out, 512, 0, b_out, 1.0f, 512);
}

// Round 2
// 185.359 us; speedup vs baseline: 2.1456x; 2.1456x over previous
//
#include <hip/hip_runtime.h>
#include <hip/hip_bf16.h>

typedef short bf16x8 __attribute__((ext_vector_type(8)));
typedef float f32x4 __attribute__((ext_vector_type(4)));

__device__ inline unsigned short f2bf(float f) {
    union { float f; unsigned u; } c; c.f = f;
    unsigned r = c.u + 0x7fffu + ((c.u >> 16) & 1u);
    return (unsigned short)(r >> 16);
}
__device__ inline float bf2f(unsigned short u) {
    union { unsigned u; float f; } c; c.u = ((unsigned)u) << 16; return c.f;
}

// ---------- fp32 -> bf16 convert (x4 vectorized) ----------
__global__ __launch_bounds__(256) void k_f32_to_bf16(const float* __restrict__ in,
                                                     unsigned short* __restrict__ out, int n4) {
    int i = blockIdx.x * 256 + threadIdx.x;
    if (i >= n4) return;
    f32x4 v = *(const f32x4*)&in[(size_t)i * 4];
    ushort4 o;
    o.x = f2bf(v[0]); o.y = f2bf(v[1]); o.z = f2bf(v[2]); o.w = f2bf(v[3]);
    *(ushort4*)&out[(size_t)i * 4] = o;
}

// ---------- transpose [K][N] fp32 -> [N][K] bf16 ----------
__global__ __launch_bounds__(256) void k_transpose_bf16(const float* __restrict__ in,
                                                        unsigned short* __restrict__ out,
                                                        int K, int N) {
    int idx = blockIdx.x * 256 + threadIdx.x;
    if (idx >= N * K) return;
    int n = idx / K, k = idx % K;
    out[idx] = f2bf(in[(size_t)k * N + n]);
}

// ---------- transpose V slice of qkv -> v_t[b,h,d,j] bf16 ----------
__global__ __launch_bounds__(256) void transpose_v(const unsigned short* __restrict__ qkv,
                                                   unsigned short* __restrict__ vt) {
    const int bh = blockIdx.y, b = bh >> 3, h = bh & 7;
    const int j0 = blockIdx.x * 64;
    __shared__ unsigned short tile[64][72];
    const int t = threadIdx.x;
#pragma unroll
    for (int it = 0; it < 16; ++it) {
        int idx = it * 256 + t;
        int jr = idx >> 6, col = idx & 63;
        tile[jr][col] = qkv[(size_t)(b * 1024 + j0 + jr) * 1536 + 1024 + h * 64 + col];
    }
    __syncthreads();
#pragma unroll
    for (int it = 0; it < 16; ++it) {
        int idx = it * 256 + t;
        int dr = idx >> 6, jc = idx & 63;
        vt[((size_t)bh * 64 + dr) * 1024 + j0 + jc] = tile[jc][dr];
    }
}

// ---------- generic A[M,K] * B^T[N,K] bf16 MFMA GEMM ----------
template <int BM, int BN, int BK, bool OUT_BF16, bool HAS_BIAS>
__global__ __launch_bounds__(256) void gemm_bt(
    const unsigned short* __restrict__ A, int ldA, long long sA,
    const unsigned short* __restrict__ B, int ldB, long long sB,
    void* __restrict__ Cv, int ldC, long long sC,
    const float* __restrict__ bias, float scale, int K) {
    constexpr int PAD = 8, LDR = BK + PAD;
    __shared__ __align__(16) unsigned short As[BM * LDR];
    __shared__ __align__(16) unsigned short Bs[BN * LDR];

    const int tid = threadIdx.x;
    const int lane = tid & 63, wv = tid >> 6;
    const int wm = wv >> 1, wn = wv & 1;
    constexpr int WM = BM / 2, WN = BN / 2;
    constexpr int MF = WM / 16, NF = WN / 16;
    constexpr int KG = BK / 8;

    const int m0 = blockIdx.x * BM, n0 = blockIdx.y * BN;
    A += (long long)blockIdx.z * sA;
    B += (long long)blockIdx.z * sB;

    const int lr = lane & 15, lk = (lane >> 4) * 8;

    f32x4 acc[MF][NF];
#pragma unroll
    for (int m = 0; m < MF; ++m)
#pragma unroll
        for (int n = 0; n < NF; ++n) acc[m][n] = (f32x4){0.f, 0.f, 0.f, 0.f};

    for (int k0 = 0; k0 < K; k0 += BK) {
#pragma unroll
        for (int i = 0; i < BM * KG / 256; ++i) {
            int c = i * 256 + tid;
            int row = c / KG, kg = c % KG;
            *(bf16x8*)&As[row * LDR + kg * 8] =
                *(const bf16x8*)&A[(size_t)(m0 + row) * ldA + k0 + kg * 8];
        }
#pragma unroll
        for (int i = 0; i < BN * KG / 256; ++i) {
            int c = i * 256 + tid;
            int row = c / KG, kg = c % KG;
            *(bf16x8*)&Bs[row * LDR + kg * 8] =
                *(const bf16x8*)&B[(size_t)(n0 + row) * ldB + k0 + kg * 8];
        }
        __syncthreads();
#pragma unroll
        for (int kk = 0; kk < BK; kk += 32) {
            bf16x8 af[MF], bfr[NF];
#pragma unroll
            for (int m = 0; m < MF; ++m)
                af[m] = *(const bf16x8*)&As[(wm * WM + m * 16 + lr) * LDR + kk + lk];
#pragma unroll
            for (int n = 0; n < NF; ++n)
                bfr[n] = *(const bf16x8*)&Bs[(wn * WN + n * 16 + lr) * LDR + kk + lk];
#pragma unroll
            for (int m = 0; m < MF; ++m)
#pragma unroll
                for (int n = 0; n < NF; ++n)
                    acc[m][n] = __builtin_amdgcn_mfma_f32_16x16x32_bf16(af[m], bfr[n], acc[m][n], 0, 0, 0);
        }
        __syncthreads();
    }

    const int rb = (lane >> 4) * 4;
    const long long cbase = (long long)blockIdx.z * sC;
#pragma unroll
    for (int m = 0; m < MF; ++m) {
#pragma unroll
        for (int n = 0; n < NF; ++n) {
            int col = n0 + wn * WN + n * 16 + lr;
            float bv = HAS_BIAS ? bias[col] : 0.0f;
#pragma unroll
            for (int r = 0; r < 4; ++r) {
                int row = m0 + wm * WM + m * 16 + rb + r;
                float v = acc[m][n][r] * scale + bv;
                if constexpr (OUT_BF16)
                    ((unsigned short*)Cv)[cbase + (size_t)row * ldC + col] = f2bf(v);
                else
                    ((float*)Cv)[cbase + (size_t)row * ldC + col] = v;
            }
        }
    }
}

// ---------- fused flash attention: softmax stats + softmax + remix + LN + PV ----------
// grid: 256 blocks (b = blk&7 for XCD L2 locality, i-tile = blk>>3), 512 threads = 8 waves = 8 heads
__global__ __launch_bounds__(512) void attn_fused(
    const unsigned short* __restrict__ qkv,   // [8192][1536] bf16
    const unsigned short* __restrict__ vt,    // [b*8+h][64][1024] bf16
    unsigned short* __restrict__ pvout,       // [8192][512] bf16
    const float* __restrict__ Wm,
    const float* __restrict__ ln_g, const float* __restrict__ ln_b) {
    const int blk = blockIdx.x;
    const int b = blk & 7, it = blk >> 3;
    const int i0 = it * 32;
    const int tid = threadIdx.x;
    const int lane = tid & 63, h = tid >> 6;
    const int lr = lane & 15, qq = lane >> 4;

    __shared__ __align__(16) unsigned short Ks[8 * 32 * 64];   // swizzled K tile, 32KB
    __shared__ __align__(16) unsigned short Ps[32 * 32 * 8];   // [i][j][h] swizzled, 16KB
    __shared__ __align__(16) unsigned short Rs[8 * 32 * 40];   // [g][i][j] stride-40, 20KB

    // uniform weights -> scalar regs (uniform addr + restrict => s_load)
    float w[64];
#pragma unroll
    for (int z = 0; z < 64; ++z) w[z] = Wm[z];
    float gam[8], bet[8];
#pragma unroll
    for (int z = 0; z < 8; ++z) { gam[z] = ln_g[z]; bet[z] = ln_b[z]; }

    // Q B-fragments for this wave's head, i-tile (ni selects 16-row block, kk selects d-half)
    bf16x8 qf[2][2];
#pragma unroll
    for (int ni = 0; ni < 2; ++ni)
#pragma unroll
        for (int kk = 0; kk < 2; ++kk)
            qf[ni][kk] = *(const bf16x8*)&qkv[(size_t)(b * 1024 + i0 + ni * 16 + lr) * 1536 +
                                              h * 64 + kk * 32 + qq * 8];

    auto stageK = [&](int t) {
#pragma unroll
        for (int ii = 0; ii < 4; ++ii) {
            int v = ii * 512 + tid;
            int e = v * 8;
            int hh = e >> 11, rem = e & 2047;
            int j = rem >> 6, d = rem & 63;
            bf16x8 val = *(const bf16x8*)&qkv[(size_t)(b * 1024 + t * 32 + j) * 1536 + 512 + hh * 64 + d];
            unsigned off = ((unsigned)hh << 12) + ((unsigned)j << 7) + ((unsigned)d << 1);
            off ^= (unsigned)(j & 7) << 4;
            *(bf16x8*)((char*)Ks + off) = val;
        }
    };
    auto kfrag = [&](int jloc, int d0) -> bf16x8 {
        unsigned off = ((unsigned)h << 12) + ((unsigned)jloc << 7) + ((unsigned)d0 << 1);
        off ^= (unsigned)(jloc & 7) << 4;
        return *(const bf16x8*)((const char*)Ks + off);
    };
    auto computeS = [&](f32x4 (&acc)[2][2]) {
#pragma unroll
        for (int mf = 0; mf < 2; ++mf)
#pragma unroll
            for (int ni = 0; ni < 2; ++ni) acc[mf][ni] = (f32x4){0.f, 0.f, 0.f, 0.f};
#pragma unroll
        for (int kk = 0; kk < 2; ++kk) {
            bf16x8 a0 = kfrag(lr, kk * 32 + qq * 8);
            bf16x8 a1 = kfrag(16 + lr, kk * 32 + qq * 8);
#pragma unroll
            for (int ni = 0; ni < 2; ++ni) {
                acc[0][ni] = __builtin_amdgcn_mfma_f32_16x16x32_bf16(a0, qf[ni][kk], acc[0][ni], 0, 0, 0);
                acc[1][ni] = __builtin_amdgcn_mfma_f32_16x16x32_bf16(a1, qf[ni][kk], acc[1][ni], 0, 0, 0);
            }
        }
    };

    float m[2] = { -1e30f, -1e30f }, l[2] = { 0.f, 0.f };

    // ---- pass 1: softmax stats (online max/sum), S^T layout: row=j, col=i
    for (int t = 0; t < 32; ++t) {
        __syncthreads();
        stageK(t);
        __syncthreads();
        f32x4 acc[2][2];
        computeS(acc);
#pragma unroll
        for (int ni = 0; ni < 2; ++ni) {
            float tmax = -1e30f;
#pragma unroll
            for (int mf = 0; mf < 2; ++mf)
#pragma unroll
                for (int rr = 0; rr < 4; ++rr) tmax = fmaxf(tmax, acc[mf][ni][rr]);
            tmax *= 0.125f;
            tmax = fmaxf(tmax, __shfl_xor(tmax, 16));
            tmax = fmaxf(tmax, __shfl_xor(tmax, 32));
            float mn = fmaxf(m[ni], tmax);
            float ts = 0.f;
#pragma unroll
            for (int mf = 0; mf < 2; ++mf)
#pragma unroll
                for (int rr = 0; rr < 4; ++rr) ts += __expf(acc[mf][ni][rr] * 0.125f - mn);
            ts += __shfl_xor(ts, 16);
            ts += __shfl_xor(ts, 32);
            l[ni] = l[ni] * __expf(m[ni] - mn) + ts;
            m[ni] = mn;
        }
    }

    float invl[2] = { 1.f / l[0], 1.f / l[1] };
    f32x4 o[2][4];
#pragma unroll
    for (int mf = 0; mf < 2; ++mf)
#pragma unroll
        for (int nd = 0; nd < 4; ++nd) o[mf][nd] = (f32x4){0.f, 0.f, 0.f, 0.f};

    __syncthreads();
    stageK(0);
    __syncthreads();

    // ---- pass 2: p -> remix -> LN -> PV
    for (int t = 0; t < 32; ++t) {
        f32x4 acc[2][2];
        computeS(acc);
        // write normalized probs to Ps[i][j][h] (bf16, swizzled)
#pragma unroll
        for (int ni = 0; ni < 2; ++ni)
#pragma unroll
            for (int mf = 0; mf < 2; ++mf)
#pragma unroll
                for (int rr = 0; rr < 4; ++rr) {
                    float p = __expf(acc[mf][ni][rr] * 0.125f - m[ni]) * invl[ni];
                    int i = ni * 16 + lr;
                    int j = mf * 16 + qq * 4 + rr;
                    unsigned off = ((unsigned)i << 9) + ((unsigned)j << 4) + ((unsigned)h << 1);
                    off ^= (unsigned)(i & 7) << 4;
                    *(unsigned short*)((char*)Ps + off) = f2bf(p);
                }
        __syncthreads();  // A: Ps complete
        if (t < 31) stageK(t + 1);  // overlap next K stage with remix
        {
            // each wave owns positions (mf=0,1; ni = h>>2; rr = h&3) -> each (i,j) computed once
            const int i = (h >> 2) * 16 + lr;
            const int r0 = h & 3;
#pragma unroll
            for (int mf = 0; mf < 2; ++mf) {
                int j = mf * 16 + qq * 4 + r0;
                unsigned off = (((unsigned)i << 9) + ((unsigned)j << 4)) ^ ((unsigned)(i & 7) << 4);
                bf16x8 p8v = *(const bf16x8*)((const char*)Ps + off);
                float mix[8];
#pragma unroll
                for (int g = 0; g < 8; ++g) mix[g] = 0.f;
#pragma unroll
                for (int hh = 0; hh < 8; ++hh) {
                    float p = bf2f((unsigned short)p8v[hh]);
#pragma unroll
                    for (int g = 0; g < 8; ++g) mix[g] = fmaf(p, w[hh * 8 + g], mix[g]);
                }
                float mu = 0.f;
#pragma unroll
                for (int g = 0; g < 8; ++g) mu += mix[g];
                mu *= 0.125f;
                float var = 0.f;
#pragma unroll
                for (int g = 0; g < 8; ++g) { float dd = mix[g] - mu; var += dd * dd; }
                var *= 0.125f;
                float rs = rsqrtf(var + 1e-5f);
#pragma unroll
                for (int g = 0; g < 8; ++g)
                    Rs[g * 1280 + i * 40 + j] = f2bf((mix[g] - mu) * rs * gam[g] + bet[g]);
            }
        }
        __syncthreads();  // B: Rs complete (also fences K restage)
        {
            bf16x8 a0 = *(const bf16x8*)&Rs[h * 1280 + lr * 40 + qq * 8];
            bf16x8 a1 = *(const bf16x8*)&Rs[h * 1280 + (16 + lr) * 40 + qq * 8];
#pragma unroll
            for (int nd = 0; nd < 4; ++nd) {
                bf16x8 bv = *(const bf16x8*)&vt[((size_t)(b * 8 + h) * 64 + nd * 16 + lr) * 1024 +
                                                t * 32 + qq * 8];
                o[0][nd] = __builtin_amdgcn_mfma_f32_16x16x32_bf16(a0, bv, o[0][nd], 0, 0, 0);
                o[1][nd] = __builtin_amdgcn_mfma_f32_16x16x32_bf16(a1, bv, o[1][nd], 0, 0, 0);
            }
        }
        // no barrier needed here: next Ps write is fenced by barrier A, Rs reads done before next A
    }

    // epilogue: O[i][d] -> pvout[b*1024+i][h*64+d]
#pragma unroll
    for (int mf = 0; mf < 2; ++mf)
#pragma unroll
        for (int nd = 0; nd < 4; ++nd)
#pragma unroll
            for (int rr = 0; rr < 4; ++rr) {
                int i = i0 + mf * 16 + qq * 4 + rr;
                int d = nd * 16 + lr;
                pvout[(size_t)(b * 1024 + i) * 512 + h * 64 + d] = f2bf(o[mf][nd][rr]);
            }
}

extern "C" void kernel_launch(void* const* d_in, const int* in_sizes, int n_in,
                              void* d_out, int out_size, void* d_ws, size_t ws_size,
                              hipStream_t stream) {
    const float* x        = (const float*)d_in[0];
    const float* w_qkv    = (const float*)d_in[1];
    const float* reattn_w = (const float*)d_in[2];
    const float* ln_g     = (const float*)d_in[3];
    const float* ln_b     = (const float*)d_in[4];
    const float* w_out    = (const float*)d_in[5];
    const float* b_out    = (const float*)d_in[6];
    float* out = (float*)d_out;

    char* ws = (char*)d_ws;
    unsigned short* x_bf  = (unsigned short*)(ws + 0);          //  8 MB  [8192][512]
    unsigned short* wqkvT = (unsigned short*)(ws + 8388608);    //  1.5MB [1536][512]
    unsigned short* woutT = (unsigned short*)(ws + 9961472);    //  0.5MB [512][512]
    unsigned short* qkv   = (unsigned short*)(ws + 10485760);   // 24 MB  [8192][1536]
    unsigned short* v_t   = (unsigned short*)(ws + 35651584);   //  8 MB  [64][64][1024]
    unsigned short* pv    = (unsigned short*)(ws + 44040192);   //  8 MB  [8192][512]

    k_f32_to_bf16<<<4096, 256, 0, stream>>>(x, x_bf, 1048576);
    k_transpose_bf16<<<3072, 256, 0, stream>>>(w_qkv, wqkvT, 512, 1536);
    k_transpose_bf16<<<1024, 256, 0, stream>>>(w_out, woutT, 512, 512);

    // qkv = x @ w_qkv   (M=8192, N=1536, K=512)
    gemm_bt<128, 128, 64, true, false><<<dim3(64, 12, 1), 256, 0, stream>>>(
        x_bf, 512, 0, wqkvT, 512, 0, qkv, 1536, 0, nullptr, 1.0f, 512);

    transpose_v<<<dim3(16, 64), 256, 0, stream>>>(qkv, v_t);

    // fused attention (both passes, all b/h)
    attn_fused<<<256, 512, 0, stream>>>(qkv, v_t, pv, reattn_w, ln_g, ln_b);

    // out = pv @ w_out + b_out   (M=8192, N=512, K=512), fp32 out
    gemm_bt<128, 128, 64, false, true><<<dim3(64, 4, 1), 256, 0, stream>>>(
        pv, 512, 0, woutT, 512, 0, out, 512, 0, b_out, 1.0f, 512);
}